// Round 11
// baseline (92.089 us; speedup 1.0000x reference)
//
#include <hip/hip_runtime.h>

// GatingNetwork: router GEMM via 3-term bf16-split MFMA + fused softmax/double top-k
// Round 11: cross-iteration split pipelining. The split3(A)->MFMA true dependency
// serialized VALU and MFMA phases across all waves (pipe-sum ~= measured 46us).
// Now split(kt+1) runs during MFMA(kt) (independent), loads pinned early via
// sched_barrier(0), full unroll for static xs[kt&1] indexing. Reg-staged A with
// XOR-swizzled double-buffer LDS (64KB exact, part overlays).
// x: [16384, 2048] f32, W: [64, 2048] f32
// out (f32 flat): topk_idx[16384,2] | topk_weights[16384,2] | probs[16384,64] | topc_idx[16384,8]

typedef __attribute__((ext_vector_type(8))) short short8;   // 8 bf16 = 4 VGPR (MFMA A/B frag)
typedef __attribute__((ext_vector_type(4))) float f32x4;    // MFMA C/D frag

constexpr int Bq = 16384;
constexpr int Dk = 2048;
constexpr int Me = 64;
constexpr int WAVES = 8;
constexpr int ROWS = 32;             // rows per block (all waves share them)
constexpr int KCHUNK = Dk / WAVES;   // 256
constexpr int NT = KCHUNK / 32;      // 8 k-tiles per wave

constexpr size_t OFF_TOPK_IDX = 0;
constexpr size_t OFF_TOPK_W   = (size_t)Bq * 2;
constexpr size_t OFF_PROBS    = (size_t)Bq * 4;
constexpr size_t OFF_TOPC_IDX = (size_t)Bq * 4 + (size_t)Bq * 64;

// packed f32x2 -> 2 bf16 (RNE, v_cvt_pk_bf16_f32); low16 = lo, high16 = hi
__device__ __forceinline__ unsigned f2bf2(float lo, float hi) {
  unsigned r;
  asm("v_cvt_pk_bf16_f32 %0, %1, %2" : "=v"(r) : "v"(lo), "v"(hi));
  return r;
}
__device__ __forceinline__ float bflo(unsigned u) { return __builtin_bit_cast(float, u << 16); }
__device__ __forceinline__ float bfhi(unsigned u) { return __builtin_bit_cast(float, u & 0xFFFF0000u); }

// split 8 f32 -> 3 short8 bf16 fragments (telescoping residuals)
__device__ __forceinline__ void split3(const float af[8], short8& s0, short8& s1, short8& s2) {
  uint4 q0, q1, q2;
  unsigned* p0 = &q0.x; unsigned* p1 = &q1.x; unsigned* p2 = &q2.x;
  #pragma unroll
  for (int p = 0; p < 4; ++p) {
    float a = af[2 * p], b = af[2 * p + 1];
    unsigned c0 = f2bf2(a, b);
    float r0a = a - bflo(c0), r0b = b - bfhi(c0);
    unsigned c1 = f2bf2(r0a, r0b);
    float r1a = r0a - bflo(c1), r1b = r0b - bfhi(c1);
    unsigned c2 = f2bf2(r1a, r1b);
    p0[p] = c0; p1[p] = c1; p2[p] = c2;
  }
  s0 = __builtin_bit_cast(short8, q0);
  s1 = __builtin_bit_cast(short8, q1);
  s2 = __builtin_bit_cast(short8, q2);
}

// ---- prep: split W f32 -> 3 bf16 planes, FRAGMENT-PACKED: [kt][n][lane][8] ----
// element (kt,n,L,j) = W[n*16 + (L&15)][kt*32 + (L>>4)*8 + j]
__global__ void wsplit_kernel(const float* __restrict__ W,
                              unsigned short* __restrict__ w0,
                              unsigned short* __restrict__ w1,
                              unsigned short* __restrict__ w2) {
  int t = blockIdx.x * blockDim.x + threadIdx.x;  // 0..16383
  int kt = t >> 8, n = (t >> 6) & 3, L = t & 63;
  int e  = n * 16 + (L & 15);
  int kb = kt * 32 + ((L >> 4) << 3);
  const float* src = W + (size_t)e * Dk + kb;
  float4 a = *reinterpret_cast<const float4*>(src);
  float4 b = *reinterpret_cast<const float4*>(src + 4);
  float af[8] = {a.x, a.y, a.z, a.w, b.x, b.y, b.z, b.w};
  short8 s0, s1, s2;
  split3(af, s0, s1, s2);
  *reinterpret_cast<short8*>(w0 + (size_t)t * 8) = s0;
  *reinterpret_cast<short8*>(w1 + (size_t)t * 8) = s1;
  *reinterpret_cast<short8*>(w2 + (size_t)t * 8) = s2;
}

// ---- main: 512 threads = 8 waves; all waves share 32 rows, each owns 1/8 of K ----
__global__ __launch_bounds__(512, 4)
void gating_mfma(const float* __restrict__ x,
                 const unsigned short* __restrict__ w0,
                 const unsigned short* __restrict__ w1,
                 const unsigned short* __restrict__ w2,
                 float* __restrict__ out) {
  // xa: [buf(2)][wave(8)][row(32)][f32 col(32)] = 65536 B exactly; part overlays post-loop
  __shared__ __align__(16) float smem[2 * WAVES * ROWS * 32];
  typedef float PartT[ROWS][64];
  PartT* part = reinterpret_cast<PartT*>(smem);

  const int tid  = threadIdx.x;
  const int wv   = tid >> 6;      // wave id = K-chunk id (0..7)
  const int L    = tid & 63;
  const int lidx = L & 15;        // A: row within 16-group; B: expert within N-tile
  const int kgrp = L >> 4;        // k-octet group 0..3
  const int rowBase = blockIdx.x * ROWS;
  const int kBase = wv * KCHUNK;

  // staging lane mapping: lane L handles row srow(+8g), global 16B-unit (L&7)
  const int srow = L >> 3;           // 0..7
  const int sc4  = (L & 7) << 2;     // global f32 col 0,4,..,28
  const float* xg0 = x + (size_t)(rowBase +      srow) * Dk + kBase + sc4;
  const float* xg1 = x + (size_t)(rowBase +  8 + srow) * Dk + kBase + sc4;
  const float* xg2 = x + (size_t)(rowBase + 16 + srow) * Dk + kBase + sc4;
  const float* xg3 = x + (size_t)(rowBase + 24 + srow) * Dk + kBase + sc4;

  // LDS addressing with XOR-unit swizzle: row R, global unit u lives at phys u^(R&7)
  float* tile0 = smem + (size_t)wv * (ROWS * 32);
  float* tile1 = smem + (size_t)(WAVES + wv) * (ROWS * 32);
  const int uW = ((L & 7) ^ (srow & 7)) << 2;   // write phys col (f32)
  const int s7 = lidx & 7;
  const int uR0 = (((2 * kgrp)     ^ s7) << 2); // read phys col for unit 2k
  const int uR1 = (((2 * kgrp + 1) ^ s7) << 2);

  // B fragment base (shorts): global k-tile ktg -> ktg*2048 + n*512 + L*8
  const size_t bbase = (size_t)kBase * 64 + (size_t)L * 8;

  f32x4 acc[2][4];
  #pragma unroll
  for (int rg = 0; rg < 2; ++rg)
    #pragma unroll
    for (int n = 0; n < 4; ++n) acc[rg][n] = (f32x4){0.f, 0.f, 0.f, 0.f};

  short8 xs[2][6];  // [phase][ x0rg0, x1rg0, x2rg0, x0rg1, x1rg1, x2rg1 ]

  // ---- prologue: tile0 -> LDS buf0; read+split A(0); tile1 -> h regs ----
  float4 h0 = *reinterpret_cast<const float4*>(xg0);
  float4 h1 = *reinterpret_cast<const float4*>(xg1);
  float4 h2 = *reinterpret_cast<const float4*>(xg2);
  float4 h3 = *reinterpret_cast<const float4*>(xg3);
  *reinterpret_cast<float4*>(tile0 + (     srow) * 32 + uW) = h0;
  *reinterpret_cast<float4*>(tile0 + ( 8 + srow) * 32 + uW) = h1;
  *reinterpret_cast<float4*>(tile0 + (16 + srow) * 32 + uW) = h2;
  *reinterpret_cast<float4*>(tile0 + (24 + srow) * 32 + uW) = h3;
  h0 = *reinterpret_cast<const float4*>(xg0 + 32);
  h1 = *reinterpret_cast<const float4*>(xg1 + 32);
  h2 = *reinterpret_cast<const float4*>(xg2 + 32);
  h3 = *reinterpret_cast<const float4*>(xg3 + 32);
  {
    float4 r0 = *reinterpret_cast<const float4*>(tile0 + (     lidx) * 32 + uR0);
    float4 r1 = *reinterpret_cast<const float4*>(tile0 + (     lidx) * 32 + uR1);
    float4 r2 = *reinterpret_cast<const float4*>(tile0 + (16 + lidx) * 32 + uR0);
    float4 r3 = *reinterpret_cast<const float4*>(tile0 + (16 + lidx) * 32 + uR1);
    float af0[8] = {r0.x, r0.y, r0.z, r0.w, r1.x, r1.y, r1.z, r1.w};
    float af1[8] = {r2.x, r2.y, r2.z, r2.w, r3.x, r3.y, r3.z, r3.w};
    split3(af0, xs[0][0], xs[0][1], xs[0][2]);
    split3(af1, xs[0][3], xs[0][4], xs[0][5]);
  }

  #pragma unroll
  for (int kt = 0; kt < NT; ++kt) {
    const int p = kt & 1, q = p ^ 1;
    const size_t to = bbase + (size_t)kt * 2048;

    // (1) B loads first (oldest): their waits never drain the x h-loads below
    short8 b0[4], b1[4], b2[4];
    #pragma unroll
    for (int n = 0; n < 4; ++n) b0[n] = *reinterpret_cast<const short8*>(w0 + to + n * 512);
    #pragma unroll
    for (int n = 0; n < 4; ++n) b1[n] = *reinterpret_cast<const short8*>(w1 + to + n * 512);
    #pragma unroll
    for (int n = 0; n < 4; ++n) b2[n] = *reinterpret_cast<const short8*>(w2 + to + n * 512);

    float4 r0, r1, r2, r3;
    if (kt + 1 < NT) {
      // (2) ds_write tile kt+1 (h loaded last iter, age ~1 iter -> no stall)
      float* wb = ((kt + 1) & 1) ? tile1 : tile0;
      *reinterpret_cast<float4*>(wb + (     srow) * 32 + uW) = h0;
      *reinterpret_cast<float4*>(wb + ( 8 + srow) * 32 + uW) = h1;
      *reinterpret_cast<float4*>(wb + (16 + srow) * 32 + uW) = h2;
      *reinterpret_cast<float4*>(wb + (24 + srow) * 32 + uW) = h3;
      // (3) h loads for tile kt+2 (newest; drained only at next iter's ds_write)
      if (kt + 2 < NT) {
        h0 = *reinterpret_cast<const float4*>(xg0 + (kt + 2) * 32);
        h1 = *reinterpret_cast<const float4*>(xg1 + (kt + 2) * 32);
        h2 = *reinterpret_cast<const float4*>(xg2 + (kt + 2) * 32);
        h3 = *reinterpret_cast<const float4*>(xg3 + (kt + 2) * 32);
      }
      // (4) ds_read A(kt+1) fragments
      r0 = *reinterpret_cast<const float4*>(wb + (     lidx) * 32 + uR0);
      r1 = *reinterpret_cast<const float4*>(wb + (     lidx) * 32 + uR1);
      r2 = *reinterpret_cast<const float4*>(wb + (16 + lidx) * 32 + uR0);
      r3 = *reinterpret_cast<const float4*>(wb + (16 + lidx) * 32 + uR1);
    }

    // pin all loads/LDS ops above; compute region below interleaves freely
    __builtin_amdgcn_sched_barrier(0);

    // (5) split(kt+1) — independent of MFMA(kt): VALU fills MFMA shadow
    if (kt + 1 < NT) {
      float af0[8] = {r0.x, r0.y, r0.z, r0.w, r1.x, r1.y, r1.z, r1.w};
      float af1[8] = {r2.x, r2.y, r2.z, r2.w, r3.x, r3.y, r3.z, r3.w};
      split3(af0, xs[q][0], xs[q][1], xs[q][2]);
      split3(af1, xs[q][3], xs[q][4], xs[q][5]);
    }

    // (6) MFMA(kt): plane 0 (x0,x1,x2), plane 1 (x0,x1), plane 2 (x0)
    #pragma unroll
    for (int n = 0; n < 4; ++n) acc[0][n] = __builtin_amdgcn_mfma_f32_16x16x32_bf16(xs[p][0], b0[n], acc[0][n], 0, 0, 0);
    #pragma unroll
    for (int n = 0; n < 4; ++n) acc[1][n] = __builtin_amdgcn_mfma_f32_16x16x32_bf16(xs[p][3], b0[n], acc[1][n], 0, 0, 0);
    #pragma unroll
    for (int n = 0; n < 4; ++n) acc[0][n] = __builtin_amdgcn_mfma_f32_16x16x32_bf16(xs[p][1], b0[n], acc[0][n], 0, 0, 0);
    #pragma unroll
    for (int n = 0; n < 4; ++n) acc[1][n] = __builtin_amdgcn_mfma_f32_16x16x32_bf16(xs[p][4], b0[n], acc[1][n], 0, 0, 0);
    #pragma unroll
    for (int n = 0; n < 4; ++n) acc[0][n] = __builtin_amdgcn_mfma_f32_16x16x32_bf16(xs[p][2], b0[n], acc[0][n], 0, 0, 0);
    #pragma unroll
    for (int n = 0; n < 4; ++n) acc[1][n] = __builtin_amdgcn_mfma_f32_16x16x32_bf16(xs[p][5], b0[n], acc[1][n], 0, 0, 0);

    #pragma unroll
    for (int n = 0; n < 4; ++n) acc[0][n] = __builtin_amdgcn_mfma_f32_16x16x32_bf16(xs[p][0], b1[n], acc[0][n], 0, 0, 0);
    #pragma unroll
    for (int n = 0; n < 4; ++n) acc[1][n] = __builtin_amdgcn_mfma_f32_16x16x32_bf16(xs[p][3], b1[n], acc[1][n], 0, 0, 0);
    #pragma unroll
    for (int n = 0; n < 4; ++n) acc[0][n] = __builtin_amdgcn_mfma_f32_16x16x32_bf16(xs[p][1], b1[n], acc[0][n], 0, 0, 0);
    #pragma unroll
    for (int n = 0; n < 4; ++n) acc[1][n] = __builtin_amdgcn_mfma_f32_16x16x32_bf16(xs[p][4], b1[n], acc[1][n], 0, 0, 0);

    #pragma unroll
    for (int n = 0; n < 4; ++n) acc[0][n] = __builtin_amdgcn_mfma_f32_16x16x32_bf16(xs[p][0], b2[n], acc[0][n], 0, 0, 0);
    #pragma unroll
    for (int n = 0; n < 4; ++n) acc[1][n] = __builtin_amdgcn_mfma_f32_16x16x32_bf16(xs[p][5 - 2], b2[n], acc[1][n], 0, 0, 0);  // xs[p][3] = x0 rg1
  }

  // all waves done with xa before part overlays it
  __syncthreads();

  // scatter partial D: row = rg*16 + kgrp*4 + r, col = n*16 + lidx  [m89-verified]
  #pragma unroll
  for (int rg = 0; rg < 2; ++rg)
    #pragma unroll
    for (int n = 0; n < 4; ++n)
      #pragma unroll
      for (int r = 0; r < 4; ++r)
        part[wv][rg * 16 + kgrp * 4 + r][n * 16 + lidx] = acc[rg][n][r];
  __syncthreads();

  // ---- epilogue: 16 threads per row, each owns 4 logit columns ----
  const int row = tid >> 4;        // 0..31
  const int g   = tid & 15;
  const int c4  = g * 4;
  const size_t grow = (size_t)rowBase + row;

  float4 v = {0.f, 0.f, 0.f, 0.f};
  #pragma unroll
  for (int pp = 0; pp < WAVES; ++pp) {
    float4 t = *reinterpret_cast<const float4*>(&part[pp][row][c4]);
    v.x += t.x; v.y += t.y; v.z += t.z; v.w += t.w;
  }
  float pv[4] = {v.x, v.y, v.z, v.w};

  // softmax over 64 via width-16 butterflies
  float mx = fmaxf(fmaxf(pv[0], pv[1]), fmaxf(pv[2], pv[3]));
  #pragma unroll
  for (int m = 1; m < 16; m <<= 1) mx = fmaxf(mx, __shfl_xor(mx, m));
  float e[4], sum = 0.f;
  #pragma unroll
  for (int j = 0; j < 4; ++j) { e[j] = expf(pv[j] - mx); sum += e[j]; }
  #pragma unroll
  for (int m = 1; m < 16; m <<= 1) sum += __shfl_xor(sum, m);
  const float inv = 1.f / (sum + 1e-12f);
  float4 pw = {e[0] * inv, e[1] * inv, e[2] * inv, e[3] * inv};
  *reinterpret_cast<float4*>(out + OFF_PROBS + grow * 64 + c4) = pw;

  // top-8: 8 masked argmax passes; tie-break = lowest index (matches jax/np)
  unsigned taken = 0;
  int bidx0 = 0, bidx1 = 0;
  float tv0 = 0.f, tv1 = 0.f;
  #pragma unroll 1
  for (int rank = 0; rank < 8; ++rank) {
    float best = -3.4e38f;
    int bl = -1;
    #pragma unroll
    for (int j = 0; j < 4; ++j)
      if (!((taken >> j) & 1u) && pv[j] > best) { best = pv[j]; bl = j; }
    int bidx = (bl >= 0) ? (c4 + bl) : (1 << 30);
    #pragma unroll
    for (int m = 1; m < 16; m <<= 1) {
      float ov = __shfl_xor(best, m);
      int   oi = __shfl_xor(bidx, m);
      if (ov > best || (ov == best && oi < bidx)) { best = ov; bidx = oi; }
    }
    if (bidx >= c4 && bidx < c4 + 4) taken |= 1u << (bidx - c4);
    if (g == 0) out[OFF_TOPC_IDX + grow * 8 + rank] = (float)bidx;
    if (rank == 0) { tv0 = best; bidx0 = bidx; }
    if (rank == 1) { tv1 = best; bidx1 = bidx; }
  }

  if (g == 0) {
    out[OFF_TOPK_IDX + grow * 2 + 0] = (float)bidx0;
    out[OFF_TOPK_IDX + grow * 2 + 1] = (float)bidx1;
    const float e1  = expf(tv1 - tv0);
    const float den = 1.f + e1 + 1e-12f;
    out[OFF_TOPK_W + grow * 2 + 0] = 1.f / den;
    out[OFF_TOPK_W + grow * 2 + 1] = e1 / den;
  }
}

extern "C" void kernel_launch(void* const* d_in, const int* in_sizes, int n_in,
                              void* d_out, int out_size, void* d_ws, size_t ws_size,
                              hipStream_t stream) {
  const float* x = (const float*)d_in[0];
  const float* W = (const float*)d_in[1];
  float* out = (float*)d_out;

  unsigned short* w0 = (unsigned short*)d_ws;
  unsigned short* w1 = w0 + (size_t)Me * Dk;
  unsigned short* w2 = w1 + (size_t)Me * Dk;

  hipLaunchKernelGGL(wsplit_kernel, dim3((Me * Dk / 8) / 256), dim3(256), 0, stream, W, w0, w1, w2);
  hipLaunchKernelGGL(gating_mfma, dim3(Bq / ROWS), dim3(512), 0, stream, x, w0, w1, w2, out);
}

// Round 12
// 53.667 us; speedup vs baseline: 1.7159x; 1.7159x over previous
//
#include <hip/hip_runtime.h>

// GatingNetwork: router GEMM via 3-term bf16-split MFMA + fused softmax/double top-k
// Round 12: round-11 pipelined structure + __launch_bounds__(512,1) (VGPR cap 256).
// Empirical cap decode on 512-thread blocks: arg=8 -> 32 regs (r7 spill), arg=4 -> 64
// regs (r6-r11; r11's pipeline state spilled: WRITE 173MB). The 64-reg corset also
// forced just-in-time B loads in r6-r10 -> ~12 exposed L1/L2 latencies per iter ->
// the 46us plateau. With 256 regs the hoisted-B + split(kt+1)-under-MFMA(kt)
// schedule can actually materialize.
// x: [16384, 2048] f32, W: [64, 2048] f32
// out (f32 flat): topk_idx[16384,2] | topk_weights[16384,2] | probs[16384,64] | topc_idx[16384,8]

typedef __attribute__((ext_vector_type(8))) short short8;   // 8 bf16 = 4 VGPR (MFMA A/B frag)
typedef __attribute__((ext_vector_type(4))) float f32x4;    // MFMA C/D frag

constexpr int Bq = 16384;
constexpr int Dk = 2048;
constexpr int Me = 64;
constexpr int WAVES = 8;
constexpr int ROWS = 32;             // rows per block (all waves share them)
constexpr int KCHUNK = Dk / WAVES;   // 256
constexpr int NT = KCHUNK / 32;      // 8 k-tiles per wave

constexpr size_t OFF_TOPK_IDX = 0;
constexpr size_t OFF_TOPK_W   = (size_t)Bq * 2;
constexpr size_t OFF_PROBS    = (size_t)Bq * 4;
constexpr size_t OFF_TOPC_IDX = (size_t)Bq * 4 + (size_t)Bq * 64;

// packed f32x2 -> 2 bf16 (RNE, v_cvt_pk_bf16_f32); low16 = lo, high16 = hi
__device__ __forceinline__ unsigned f2bf2(float lo, float hi) {
  unsigned r;
  asm("v_cvt_pk_bf16_f32 %0, %1, %2" : "=v"(r) : "v"(lo), "v"(hi));
  return r;
}
__device__ __forceinline__ float bflo(unsigned u) { return __builtin_bit_cast(float, u << 16); }
__device__ __forceinline__ float bfhi(unsigned u) { return __builtin_bit_cast(float, u & 0xFFFF0000u); }

// split 8 f32 -> 3 short8 bf16 fragments (telescoping residuals)
__device__ __forceinline__ void split3(const float af[8], short8& s0, short8& s1, short8& s2) {
  uint4 q0, q1, q2;
  unsigned* p0 = &q0.x; unsigned* p1 = &q1.x; unsigned* p2 = &q2.x;
  #pragma unroll
  for (int p = 0; p < 4; ++p) {
    float a = af[2 * p], b = af[2 * p + 1];
    unsigned c0 = f2bf2(a, b);
    float r0a = a - bflo(c0), r0b = b - bfhi(c0);
    unsigned c1 = f2bf2(r0a, r0b);
    float r1a = r0a - bflo(c1), r1b = r0b - bfhi(c1);
    unsigned c2 = f2bf2(r1a, r1b);
    p0[p] = c0; p1[p] = c1; p2[p] = c2;
  }
  s0 = __builtin_bit_cast(short8, q0);
  s1 = __builtin_bit_cast(short8, q1);
  s2 = __builtin_bit_cast(short8, q2);
}

// ---- prep: split W f32 -> 3 bf16 planes, FRAGMENT-PACKED: [kt][n][lane][8] ----
// element (kt,n,L,j) = W[n*16 + (L&15)][kt*32 + (L>>4)*8 + j]
__global__ void wsplit_kernel(const float* __restrict__ W,
                              unsigned short* __restrict__ w0,
                              unsigned short* __restrict__ w1,
                              unsigned short* __restrict__ w2) {
  int t = blockIdx.x * blockDim.x + threadIdx.x;  // 0..16383
  int kt = t >> 8, n = (t >> 6) & 3, L = t & 63;
  int e  = n * 16 + (L & 15);
  int kb = kt * 32 + ((L >> 4) << 3);
  const float* src = W + (size_t)e * Dk + kb;
  float4 a = *reinterpret_cast<const float4*>(src);
  float4 b = *reinterpret_cast<const float4*>(src + 4);
  float af[8] = {a.x, a.y, a.z, a.w, b.x, b.y, b.z, b.w};
  short8 s0, s1, s2;
  split3(af, s0, s1, s2);
  *reinterpret_cast<short8*>(w0 + (size_t)t * 8) = s0;
  *reinterpret_cast<short8*>(w1 + (size_t)t * 8) = s1;
  *reinterpret_cast<short8*>(w2 + (size_t)t * 8) = s2;
}

// ---- main: 512 threads = 8 waves; all waves share 32 rows, each owns 1/8 of K ----
__global__ __launch_bounds__(512, 1)
void gating_mfma(const float* __restrict__ x,
                 const unsigned short* __restrict__ w0,
                 const unsigned short* __restrict__ w1,
                 const unsigned short* __restrict__ w2,
                 float* __restrict__ out) {
  // xa: [buf(2)][wave(8)][row(32)][f32 col(32)] = 65536 B exactly; part overlays post-loop
  __shared__ __align__(16) float smem[2 * WAVES * ROWS * 32];
  typedef float PartT[ROWS][64];
  PartT* part = reinterpret_cast<PartT*>(smem);

  const int tid  = threadIdx.x;
  const int wv   = tid >> 6;      // wave id = K-chunk id (0..7)
  const int L    = tid & 63;
  const int lidx = L & 15;        // A: row within 16-group; B: expert within N-tile
  const int kgrp = L >> 4;        // k-octet group 0..3
  const int rowBase = blockIdx.x * ROWS;
  const int kBase = wv * KCHUNK;

  // staging lane mapping: lane L handles row srow(+8g), global 16B-unit (L&7)
  const int srow = L >> 3;           // 0..7
  const int sc4  = (L & 7) << 2;     // global f32 col 0,4,..,28
  const float* xg0 = x + (size_t)(rowBase +      srow) * Dk + kBase + sc4;
  const float* xg1 = x + (size_t)(rowBase +  8 + srow) * Dk + kBase + sc4;
  const float* xg2 = x + (size_t)(rowBase + 16 + srow) * Dk + kBase + sc4;
  const float* xg3 = x + (size_t)(rowBase + 24 + srow) * Dk + kBase + sc4;

  // LDS addressing with XOR-unit swizzle: row R, global unit u lives at phys u^(R&7)
  float* tile0 = smem + (size_t)wv * (ROWS * 32);
  float* tile1 = smem + (size_t)(WAVES + wv) * (ROWS * 32);
  const int uW = ((L & 7) ^ (srow & 7)) << 2;   // write phys col (f32)
  const int s7 = lidx & 7;
  const int uR0 = (((2 * kgrp)     ^ s7) << 2); // read phys col for unit 2k
  const int uR1 = (((2 * kgrp + 1) ^ s7) << 2);

  // B fragment base (shorts): global k-tile ktg -> ktg*2048 + n*512 + L*8
  const size_t bbase = (size_t)kBase * 64 + (size_t)L * 8;

  f32x4 acc[2][4];
  #pragma unroll
  for (int rg = 0; rg < 2; ++rg)
    #pragma unroll
    for (int n = 0; n < 4; ++n) acc[rg][n] = (f32x4){0.f, 0.f, 0.f, 0.f};

  short8 xs[2][6];  // [phase][ x0rg0, x1rg0, x2rg0, x0rg1, x1rg1, x2rg1 ]

  // ---- prologue: tile0 -> LDS buf0; read+split A(0); tile1 -> h regs ----
  float4 h0 = *reinterpret_cast<const float4*>(xg0);
  float4 h1 = *reinterpret_cast<const float4*>(xg1);
  float4 h2 = *reinterpret_cast<const float4*>(xg2);
  float4 h3 = *reinterpret_cast<const float4*>(xg3);
  *reinterpret_cast<float4*>(tile0 + (     srow) * 32 + uW) = h0;
  *reinterpret_cast<float4*>(tile0 + ( 8 + srow) * 32 + uW) = h1;
  *reinterpret_cast<float4*>(tile0 + (16 + srow) * 32 + uW) = h2;
  *reinterpret_cast<float4*>(tile0 + (24 + srow) * 32 + uW) = h3;
  h0 = *reinterpret_cast<const float4*>(xg0 + 32);
  h1 = *reinterpret_cast<const float4*>(xg1 + 32);
  h2 = *reinterpret_cast<const float4*>(xg2 + 32);
  h3 = *reinterpret_cast<const float4*>(xg3 + 32);
  {
    float4 r0 = *reinterpret_cast<const float4*>(tile0 + (     lidx) * 32 + uR0);
    float4 r1 = *reinterpret_cast<const float4*>(tile0 + (     lidx) * 32 + uR1);
    float4 r2 = *reinterpret_cast<const float4*>(tile0 + (16 + lidx) * 32 + uR0);
    float4 r3 = *reinterpret_cast<const float4*>(tile0 + (16 + lidx) * 32 + uR1);
    float af0[8] = {r0.x, r0.y, r0.z, r0.w, r1.x, r1.y, r1.z, r1.w};
    float af1[8] = {r2.x, r2.y, r2.z, r2.w, r3.x, r3.y, r3.z, r3.w};
    split3(af0, xs[0][0], xs[0][1], xs[0][2]);
    split3(af1, xs[0][3], xs[0][4], xs[0][5]);
  }

  #pragma unroll
  for (int kt = 0; kt < NT; ++kt) {
    const int p = kt & 1, q = p ^ 1;
    const size_t to = bbase + (size_t)kt * 2048;

    // (1) B loads first (oldest): their waits never drain the x h-loads below
    short8 b0[4], b1[4], b2[4];
    #pragma unroll
    for (int n = 0; n < 4; ++n) b0[n] = *reinterpret_cast<const short8*>(w0 + to + n * 512);
    #pragma unroll
    for (int n = 0; n < 4; ++n) b1[n] = *reinterpret_cast<const short8*>(w1 + to + n * 512);
    #pragma unroll
    for (int n = 0; n < 4; ++n) b2[n] = *reinterpret_cast<const short8*>(w2 + to + n * 512);

    float4 r0, r1, r2, r3;
    if (kt + 1 < NT) {
      // (2) ds_write tile kt+1 (h loaded last iter, age ~1 iter -> no stall)
      float* wb = ((kt + 1) & 1) ? tile1 : tile0;
      *reinterpret_cast<float4*>(wb + (     srow) * 32 + uW) = h0;
      *reinterpret_cast<float4*>(wb + ( 8 + srow) * 32 + uW) = h1;
      *reinterpret_cast<float4*>(wb + (16 + srow) * 32 + uW) = h2;
      *reinterpret_cast<float4*>(wb + (24 + srow) * 32 + uW) = h3;
      // (3) h loads for tile kt+2 (newest; drained only at next iter's ds_write)
      if (kt + 2 < NT) {
        h0 = *reinterpret_cast<const float4*>(xg0 + (kt + 2) * 32);
        h1 = *reinterpret_cast<const float4*>(xg1 + (kt + 2) * 32);
        h2 = *reinterpret_cast<const float4*>(xg2 + (kt + 2) * 32);
        h3 = *reinterpret_cast<const float4*>(xg3 + (kt + 2) * 32);
      }
      // (4) ds_read A(kt+1) fragments
      r0 = *reinterpret_cast<const float4*>(wb + (     lidx) * 32 + uR0);
      r1 = *reinterpret_cast<const float4*>(wb + (     lidx) * 32 + uR1);
      r2 = *reinterpret_cast<const float4*>(wb + (16 + lidx) * 32 + uR0);
      r3 = *reinterpret_cast<const float4*>(wb + (16 + lidx) * 32 + uR1);
    }

    // pin all loads/LDS ops above; compute region below interleaves freely
    __builtin_amdgcn_sched_barrier(0);

    // (5) split(kt+1) — independent of MFMA(kt): VALU fills MFMA shadow
    if (kt + 1 < NT) {
      float af0[8] = {r0.x, r0.y, r0.z, r0.w, r1.x, r1.y, r1.z, r1.w};
      float af1[8] = {r2.x, r2.y, r2.z, r2.w, r3.x, r3.y, r3.z, r3.w};
      split3(af0, xs[q][0], xs[q][1], xs[q][2]);
      split3(af1, xs[q][3], xs[q][4], xs[q][5]);
    }

    // (6) MFMA(kt): plane 0 (x0,x1,x2), plane 1 (x0,x1), plane 2 (x0)
    #pragma unroll
    for (int n = 0; n < 4; ++n) acc[0][n] = __builtin_amdgcn_mfma_f32_16x16x32_bf16(xs[p][0], b0[n], acc[0][n], 0, 0, 0);
    #pragma unroll
    for (int n = 0; n < 4; ++n) acc[1][n] = __builtin_amdgcn_mfma_f32_16x16x32_bf16(xs[p][3], b0[n], acc[1][n], 0, 0, 0);
    #pragma unroll
    for (int n = 0; n < 4; ++n) acc[0][n] = __builtin_amdgcn_mfma_f32_16x16x32_bf16(xs[p][1], b0[n], acc[0][n], 0, 0, 0);
    #pragma unroll
    for (int n = 0; n < 4; ++n) acc[1][n] = __builtin_amdgcn_mfma_f32_16x16x32_bf16(xs[p][4], b0[n], acc[1][n], 0, 0, 0);
    #pragma unroll
    for (int n = 0; n < 4; ++n) acc[0][n] = __builtin_amdgcn_mfma_f32_16x16x32_bf16(xs[p][2], b0[n], acc[0][n], 0, 0, 0);
    #pragma unroll
    for (int n = 0; n < 4; ++n) acc[1][n] = __builtin_amdgcn_mfma_f32_16x16x32_bf16(xs[p][5], b0[n], acc[1][n], 0, 0, 0);

    #pragma unroll
    for (int n = 0; n < 4; ++n) acc[0][n] = __builtin_amdgcn_mfma_f32_16x16x32_bf16(xs[p][0], b1[n], acc[0][n], 0, 0, 0);
    #pragma unroll
    for (int n = 0; n < 4; ++n) acc[1][n] = __builtin_amdgcn_mfma_f32_16x16x32_bf16(xs[p][3], b1[n], acc[1][n], 0, 0, 0);
    #pragma unroll
    for (int n = 0; n < 4; ++n) acc[0][n] = __builtin_amdgcn_mfma_f32_16x16x32_bf16(xs[p][1], b1[n], acc[0][n], 0, 0, 0);
    #pragma unroll
    for (int n = 0; n < 4; ++n) acc[1][n] = __builtin_amdgcn_mfma_f32_16x16x32_bf16(xs[p][4], b1[n], acc[1][n], 0, 0, 0);

    #pragma unroll
    for (int n = 0; n < 4; ++n) acc[0][n] = __builtin_amdgcn_mfma_f32_16x16x32_bf16(xs[p][0], b2[n], acc[0][n], 0, 0, 0);
    #pragma unroll
    for (int n = 0; n < 4; ++n) acc[1][n] = __builtin_amdgcn_mfma_f32_16x16x32_bf16(xs[p][3], b2[n], acc[1][n], 0, 0, 0);
  }

  // all waves done with xa before part overlays it
  __syncthreads();

  // scatter partial D: row = rg*16 + kgrp*4 + r, col = n*16 + lidx  [m89-verified]
  #pragma unroll
  for (int rg = 0; rg < 2; ++rg)
    #pragma unroll
    for (int n = 0; n < 4; ++n)
      #pragma unroll
      for (int r = 0; r < 4; ++r)
        part[wv][rg * 16 + kgrp * 4 + r][n * 16 + lidx] = acc[rg][n][r];
  __syncthreads();

  // ---- epilogue: 16 threads per row, each owns 4 logit columns ----
  const int row = tid >> 4;        // 0..31
  const int g   = tid & 15;
  const int c4  = g * 4;
  const size_t grow = (size_t)rowBase + row;

  float4 v = {0.f, 0.f, 0.f, 0.f};
  #pragma unroll
  for (int pp = 0; pp < WAVES; ++pp) {
    float4 t = *reinterpret_cast<const float4*>(&part[pp][row][c4]);
    v.x += t.x; v.y += t.y; v.z += t.z; v.w += t.w;
  }
  float pv[4] = {v.x, v.y, v.z, v.w};

  // softmax over 64 via width-16 butterflies
  float mx = fmaxf(fmaxf(pv[0], pv[1]), fmaxf(pv[2], pv[3]));
  #pragma unroll
  for (int m = 1; m < 16; m <<= 1) mx = fmaxf(mx, __shfl_xor(mx, m));
  float e[4], sum = 0.f;
  #pragma unroll
  for (int j = 0; j < 4; ++j) { e[j] = expf(pv[j] - mx); sum += e[j]; }
  #pragma unroll
  for (int m = 1; m < 16; m <<= 1) sum += __shfl_xor(sum, m);
  const float inv = 1.f / (sum + 1e-12f);
  float4 pw = {e[0] * inv, e[1] * inv, e[2] * inv, e[3] * inv};
  *reinterpret_cast<float4*>(out + OFF_PROBS + grow * 64 + c4) = pw;

  // top-8: 8 masked argmax passes; tie-break = lowest index (matches jax/np)
  unsigned taken = 0;
  int bidx0 = 0, bidx1 = 0;
  float tv0 = 0.f, tv1 = 0.f;
  #pragma unroll 1
  for (int rank = 0; rank < 8; ++rank) {
    float best = -3.4e38f;
    int bl = -1;
    #pragma unroll
    for (int j = 0; j < 4; ++j)
      if (!((taken >> j) & 1u) && pv[j] > best) { best = pv[j]; bl = j; }
    int bidx = (bl >= 0) ? (c4 + bl) : (1 << 30);
    #pragma unroll
    for (int m = 1; m < 16; m <<= 1) {
      float ov = __shfl_xor(best, m);
      int   oi = __shfl_xor(bidx, m);
      if (ov > best || (ov == best && oi < bidx)) { best = ov; bidx = oi; }
    }
    if (bidx >= c4 && bidx < c4 + 4) taken |= 1u << (bidx - c4);
    if (g == 0) out[OFF_TOPC_IDX + grow * 8 + rank] = (float)bidx;
    if (rank == 0) { tv0 = best; bidx0 = bidx; }
    if (rank == 1) { tv1 = best; bidx1 = bidx; }
  }

  if (g == 0) {
    out[OFF_TOPK_IDX + grow * 2 + 0] = (float)bidx0;
    out[OFF_TOPK_IDX + grow * 2 + 1] = (float)bidx1;
    const float e1  = expf(tv1 - tv0);
    const float den = 1.f + e1 + 1e-12f;
    out[OFF_TOPK_W + grow * 2 + 0] = 1.f / den;
    out[OFF_TOPK_W + grow * 2 + 1] = e1 / den;
  }
}

extern "C" void kernel_launch(void* const* d_in, const int* in_sizes, int n_in,
                              void* d_out, int out_size, void* d_ws, size_t ws_size,
                              hipStream_t stream) {
  const float* x = (const float*)d_in[0];
  const float* W = (const float*)d_in[1];
  float* out = (float*)d_out;

  unsigned short* w0 = (unsigned short*)d_ws;
  unsigned short* w1 = w0 + (size_t)Me * Dk;
  unsigned short* w2 = w1 + (size_t)Me * Dk;

  hipLaunchKernelGGL(wsplit_kernel, dim3((Me * Dk / 8) / 256), dim3(256), 0, stream, W, w0, w1, w2);
  hipLaunchKernelGGL(gating_mfma, dim3(Bq / ROWS), dim3(512), 0, stream, x, w0, w1, w2, out);
}

// Round 13
// 46.076 us; speedup vs baseline: 1.9986x; 1.1648x over previous
//
#include <hip/hip_runtime.h>

// GatingNetwork: router GEMM via 3-term bf16-split MFMA + fused softmax/double top-k
// Round 13: round-8 structure with __launch_bounds__(512, 2) -> VGPR cap 128.
// Cap decode (512-thr blocks, empirical): arg=8 -> 32 regs (spill, r7), arg=4 -> 64
// (JIT-B corset, r6/r8/r9/r10 plateau 46us), arg=1 -> 256 (no spill but 8 waves/CU,
// r12 54us). arg=2 = 128 regs x 4 waves/SIMD: B-frags can be hoisted AND two blocks
// stay co-resident. Clean A/B vs r8 (46.43us), only the bound changes.
// x: [16384, 2048] f32, W: [64, 2048] f32
// out (f32 flat): topk_idx[16384,2] | topk_weights[16384,2] | probs[16384,64] | topc_idx[16384,8]

typedef __attribute__((ext_vector_type(8))) short short8;   // 8 bf16 = 4 VGPR (MFMA A/B frag)
typedef __attribute__((ext_vector_type(4))) float f32x4;    // MFMA C/D frag

constexpr int Bq = 16384;
constexpr int Dk = 2048;
constexpr int Me = 64;
constexpr int WAVES = 8;
constexpr int ROWS = 32;             // rows per block (all waves share them)
constexpr int KCHUNK = Dk / WAVES;   // 256
constexpr int NT = KCHUNK / 32;      // 8 k-tiles per wave

constexpr size_t OFF_TOPK_IDX = 0;
constexpr size_t OFF_TOPK_W   = (size_t)Bq * 2;
constexpr size_t OFF_PROBS    = (size_t)Bq * 4;
constexpr size_t OFF_TOPC_IDX = (size_t)Bq * 4 + (size_t)Bq * 64;

// packed f32x2 -> 2 bf16 (RNE, v_cvt_pk_bf16_f32); low16 = lo, high16 = hi
__device__ __forceinline__ unsigned f2bf2(float lo, float hi) {
  unsigned r;
  asm("v_cvt_pk_bf16_f32 %0, %1, %2" : "=v"(r) : "v"(lo), "v"(hi));
  return r;
}
__device__ __forceinline__ float bflo(unsigned u) { return __builtin_bit_cast(float, u << 16); }
__device__ __forceinline__ float bfhi(unsigned u) { return __builtin_bit_cast(float, u & 0xFFFF0000u); }

// split 8 f32 -> 3 short8 bf16 fragments (telescoping residuals)
__device__ __forceinline__ void split3(const float af[8], short8& s0, short8& s1, short8& s2) {
  uint4 q0, q1, q2;
  unsigned* p0 = &q0.x; unsigned* p1 = &q1.x; unsigned* p2 = &q2.x;
  #pragma unroll
  for (int p = 0; p < 4; ++p) {
    float a = af[2 * p], b = af[2 * p + 1];
    unsigned c0 = f2bf2(a, b);
    float r0a = a - bflo(c0), r0b = b - bfhi(c0);
    unsigned c1 = f2bf2(r0a, r0b);
    float r1a = r0a - bflo(c1), r1b = r0b - bfhi(c1);
    unsigned c2 = f2bf2(r1a, r1b);
    p0[p] = c0; p1[p] = c1; p2[p] = c2;
  }
  s0 = __builtin_bit_cast(short8, q0);
  s1 = __builtin_bit_cast(short8, q1);
  s2 = __builtin_bit_cast(short8, q2);
}

// ---- prep: split W f32 -> 3 bf16 planes, FRAGMENT-PACKED: [kt][n][lane][8] ----
// element (kt,n,L,j) = W[n*16 + (L&15)][kt*32 + (L>>4)*8 + j]
__global__ void wsplit_kernel(const float* __restrict__ W,
                              unsigned short* __restrict__ w0,
                              unsigned short* __restrict__ w1,
                              unsigned short* __restrict__ w2) {
  int t = blockIdx.x * blockDim.x + threadIdx.x;  // 0..16383
  int kt = t >> 8, n = (t >> 6) & 3, L = t & 63;
  int e  = n * 16 + (L & 15);
  int kb = kt * 32 + ((L >> 4) << 3);
  const float* src = W + (size_t)e * Dk + kb;
  float4 a = *reinterpret_cast<const float4*>(src);
  float4 b = *reinterpret_cast<const float4*>(src + 4);
  float af[8] = {a.x, a.y, a.z, a.w, b.x, b.y, b.z, b.w};
  short8 s0, s1, s2;
  split3(af, s0, s1, s2);
  *reinterpret_cast<short8*>(w0 + (size_t)t * 8) = s0;
  *reinterpret_cast<short8*>(w1 + (size_t)t * 8) = s1;
  *reinterpret_cast<short8*>(w2 + (size_t)t * 8) = s2;
}

// ---- main: 512 threads = 8 waves; all waves share 32 rows, each owns 1/8 of K ----
__global__ __launch_bounds__(512, 2)
void gating_mfma(const float* __restrict__ x,
                 const unsigned short* __restrict__ w0,
                 const unsigned short* __restrict__ w1,
                 const unsigned short* __restrict__ w2,
                 float* __restrict__ out) {
  // overlay: A-stage xa[8][32][36] f32 (36864B); then part[4][32][68] f32 (34816B)
  __shared__ __align__(16) char smem[WAVES * ROWS * 36 * 4];  // 36864
  typedef float XaT[ROWS][36];
  XaT* xa = reinterpret_cast<XaT*>(smem);        // xa[wv][row][col]
  typedef float PartT[ROWS][68];
  PartT* part = reinterpret_cast<PartT*>(smem);  // part[0..3][row][col]

  const int tid  = threadIdx.x;
  const int wv   = tid >> 6;      // wave id = K-chunk id (0..7)
  const int L    = tid & 63;
  const int lidx = L & 15;        // A: row within 16-group; B: expert within N-tile
  const int kgrp = L >> 4;        // k-octet group 0..3
  const int rowBase = blockIdx.x * ROWS;
  const int kBase = wv * KCHUNK;

  // staging lane mapping: segment i covers rows i*8..i*8+7, 128B contiguous per row
  const int srow = L >> 3;           // 0..7
  const int sc4  = (L & 7) << 2;     // f32 col 0,4,..,28
  const float* xg0 = x + (size_t)(rowBase +      srow) * Dk + kBase + sc4;
  const float* xg1 = x + (size_t)(rowBase +  8 + srow) * Dk + kBase + sc4;
  const float* xg2 = x + (size_t)(rowBase + 16 + srow) * Dk + kBase + sc4;
  const float* xg3 = x + (size_t)(rowBase + 24 + srow) * Dk + kBase + sc4;

  // B fragment base (shorts): global tile ktg -> ktg*2048 + n*512 + L*8
  const size_t bbase = (size_t)kBase * 64 + (size_t)L * 8;

  f32x4 acc[2][4];
  #pragma unroll
  for (int rg = 0; rg < 2; ++rg)
    #pragma unroll
    for (int n = 0; n < 4; ++n) acc[rg][n] = (f32x4){0.f, 0.f, 0.f, 0.f};

  // prologue: tile0 -> LDS (wave-private region, no barrier needed)
  *reinterpret_cast<float4*>(&xa[wv][     srow][sc4]) = *reinterpret_cast<const float4*>(xg0);
  *reinterpret_cast<float4*>(&xa[wv][ 8 + srow][sc4]) = *reinterpret_cast<const float4*>(xg1);
  *reinterpret_cast<float4*>(&xa[wv][16 + srow][sc4]) = *reinterpret_cast<const float4*>(xg2);
  *reinterpret_cast<float4*>(&xa[wv][24 + srow][sc4]) = *reinterpret_cast<const float4*>(xg3);

  #pragma unroll 1
  for (int kt = 0; kt < NT; ++kt) {
    // A fragments for both row-groups (reads complete before the write-late below)
    float4 aLo0 = *reinterpret_cast<const float4*>(&xa[wv][     lidx][kgrp * 8]);
    float4 aHi0 = *reinterpret_cast<const float4*>(&xa[wv][     lidx][kgrp * 8 + 4]);
    float4 aLo1 = *reinterpret_cast<const float4*>(&xa[wv][16 + lidx][kgrp * 8]);
    float4 aHi1 = *reinterpret_cast<const float4*>(&xa[wv][16 + lidx][kgrp * 8 + 4]);

    // issue next-tile global loads early (latency hides under MFMA; written late)
    float4 h0, h1, h2, h3;
    if (kt < NT - 1) {
      h0 = *reinterpret_cast<const float4*>(xg0 + (kt + 1) * 32);
      h1 = *reinterpret_cast<const float4*>(xg1 + (kt + 1) * 32);
      h2 = *reinterpret_cast<const float4*>(xg2 + (kt + 1) * 32);
      h3 = *reinterpret_cast<const float4*>(xg3 + (kt + 1) * 32);
    }

    const size_t to = bbase + (size_t)kt * 2048;

    // plane-0 B loads
    short8 b0[4];
    #pragma unroll
    for (int n = 0; n < 4; ++n) b0[n] = *reinterpret_cast<const short8*>(w0 + to + n * 512);

    // split both A octets into 3 bf16 fragments each
    float af0[8] = {aLo0.x, aLo0.y, aLo0.z, aLo0.w, aHi0.x, aHi0.y, aHi0.z, aHi0.w};
    float af1[8] = {aLo1.x, aLo1.y, aLo1.z, aLo1.w, aHi1.x, aHi1.y, aHi1.z, aHi1.w};
    short8 xs00, xs10, xs20, xs01, xs11, xs21;   // xs<plane><rowgroup>
    split3(af0, xs00, xs10, xs20);
    split3(af1, xs01, xs11, xs21);

    // plane-1 B loads issued before plane-0 MFMA cluster (latency overlap)
    short8 b1[4];
    #pragma unroll
    for (int n = 0; n < 4; ++n) b1[n] = *reinterpret_cast<const short8*>(w1 + to + n * 512);

    // plane 0: x0*W0, x1*W0, x2*W0 for both row-groups (24 MFMA)
    #pragma unroll
    for (int n = 0; n < 4; ++n) acc[0][n] = __builtin_amdgcn_mfma_f32_16x16x32_bf16(xs00, b0[n], acc[0][n], 0, 0, 0);
    #pragma unroll
    for (int n = 0; n < 4; ++n) acc[1][n] = __builtin_amdgcn_mfma_f32_16x16x32_bf16(xs01, b0[n], acc[1][n], 0, 0, 0);
    #pragma unroll
    for (int n = 0; n < 4; ++n) acc[0][n] = __builtin_amdgcn_mfma_f32_16x16x32_bf16(xs10, b0[n], acc[0][n], 0, 0, 0);
    #pragma unroll
    for (int n = 0; n < 4; ++n) acc[1][n] = __builtin_amdgcn_mfma_f32_16x16x32_bf16(xs11, b0[n], acc[1][n], 0, 0, 0);
    #pragma unroll
    for (int n = 0; n < 4; ++n) acc[0][n] = __builtin_amdgcn_mfma_f32_16x16x32_bf16(xs20, b0[n], acc[0][n], 0, 0, 0);
    #pragma unroll
    for (int n = 0; n < 4; ++n) acc[1][n] = __builtin_amdgcn_mfma_f32_16x16x32_bf16(xs21, b0[n], acc[1][n], 0, 0, 0);

    // plane-2 B loads issued before plane-1 MFMA cluster
    short8 b2[4];
    #pragma unroll
    for (int n = 0; n < 4; ++n) b2[n] = *reinterpret_cast<const short8*>(w2 + to + n * 512);

    // plane 1: x0*W1, x1*W1 (16 MFMA)
    #pragma unroll
    for (int n = 0; n < 4; ++n) acc[0][n] = __builtin_amdgcn_mfma_f32_16x16x32_bf16(xs00, b1[n], acc[0][n], 0, 0, 0);
    #pragma unroll
    for (int n = 0; n < 4; ++n) acc[1][n] = __builtin_amdgcn_mfma_f32_16x16x32_bf16(xs01, b1[n], acc[1][n], 0, 0, 0);
    #pragma unroll
    for (int n = 0; n < 4; ++n) acc[0][n] = __builtin_amdgcn_mfma_f32_16x16x32_bf16(xs10, b1[n], acc[0][n], 0, 0, 0);
    #pragma unroll
    for (int n = 0; n < 4; ++n) acc[1][n] = __builtin_amdgcn_mfma_f32_16x16x32_bf16(xs11, b1[n], acc[1][n], 0, 0, 0);

    // plane 2: x0*W2 (8 MFMA)
    #pragma unroll
    for (int n = 0; n < 4; ++n) acc[0][n] = __builtin_amdgcn_mfma_f32_16x16x32_bf16(xs00, b2[n], acc[0][n], 0, 0, 0);
    #pragma unroll
    for (int n = 0; n < 4; ++n) acc[1][n] = __builtin_amdgcn_mfma_f32_16x16x32_bf16(xs01, b2[n], acc[1][n], 0, 0, 0);

    // write-late: next A tile into the (single) wave-private buffer
    if (kt < NT - 1) {
      *reinterpret_cast<float4*>(&xa[wv][     srow][sc4]) = h0;
      *reinterpret_cast<float4*>(&xa[wv][ 8 + srow][sc4]) = h1;
      *reinterpret_cast<float4*>(&xa[wv][16 + srow][sc4]) = h2;
      *reinterpret_cast<float4*>(&xa[wv][24 + srow][sc4]) = h3;
    }
  }

  // ---- two-stage K-reduce: 8 partials -> 4 (LDS) -> epilogue sums 4 ----
  // D layout: row = rg*16 + kgrp*4 + r, col = n*16 + lidx  [m89-verified]
  __syncthreads();  // xa dead everywhere; part overlays it
  if (wv >= 4) {
    #pragma unroll
    for (int rg = 0; rg < 2; ++rg)
      #pragma unroll
      for (int n = 0; n < 4; ++n)
        #pragma unroll
        for (int r = 0; r < 4; ++r)
          part[wv - 4][rg * 16 + kgrp * 4 + r][n * 16 + lidx] = acc[rg][n][r];
  }
  __syncthreads();
  if (wv < 4) {
    #pragma unroll
    for (int rg = 0; rg < 2; ++rg)
      #pragma unroll
      for (int n = 0; n < 4; ++n)
        #pragma unroll
        for (int r = 0; r < 4; ++r) {
          float s = acc[rg][n][r] + part[wv][rg * 16 + kgrp * 4 + r][n * 16 + lidx];
          part[wv][rg * 16 + kgrp * 4 + r][n * 16 + lidx] = s;
        }
  }
  __syncthreads();

  // ---- epilogue: 16 threads per row, each owns 4 logit columns ----
  const int row = tid >> 4;        // 0..31
  const int g   = tid & 15;
  const int c4  = g * 4;
  const size_t grow = (size_t)rowBase + row;

  float4 v = {0.f, 0.f, 0.f, 0.f};
  #pragma unroll
  for (int p = 0; p < 4; ++p) {
    float4 t = *reinterpret_cast<const float4*>(&part[p][row][c4]);
    v.x += t.x; v.y += t.y; v.z += t.z; v.w += t.w;
  }
  float pv[4] = {v.x, v.y, v.z, v.w};

  // softmax over 64 via width-16 butterflies
  float mx = fmaxf(fmaxf(pv[0], pv[1]), fmaxf(pv[2], pv[3]));
  #pragma unroll
  for (int m = 1; m < 16; m <<= 1) mx = fmaxf(mx, __shfl_xor(mx, m));
  float e[4], sum = 0.f;
  #pragma unroll
  for (int j = 0; j < 4; ++j) { e[j] = expf(pv[j] - mx); sum += e[j]; }
  #pragma unroll
  for (int m = 1; m < 16; m <<= 1) sum += __shfl_xor(sum, m);
  const float inv = 1.f / (sum + 1e-12f);
  float4 pw = {e[0] * inv, e[1] * inv, e[2] * inv, e[3] * inv};
  *reinterpret_cast<float4*>(out + OFF_PROBS + grow * 64 + c4) = pw;

  // top-8: 8 masked argmax passes; tie-break = lowest index (matches jax/np)
  unsigned taken = 0;
  int bidx0 = 0, bidx1 = 0;
  float tv0 = 0.f, tv1 = 0.f;
  #pragma unroll 1
  for (int rank = 0; rank < 8; ++rank) {
    float best = -3.4e38f;
    int bl = -1;
    #pragma unroll
    for (int j = 0; j < 4; ++j)
      if (!((taken >> j) & 1u) && pv[j] > best) { best = pv[j]; bl = j; }
    int bidx = (bl >= 0) ? (c4 + bl) : (1 << 30);
    #pragma unroll
    for (int m = 1; m < 16; m <<= 1) {
      float ov = __shfl_xor(best, m);
      int   oi = __shfl_xor(bidx, m);
      if (ov > best || (ov == best && oi < bidx)) { best = ov; bidx = oi; }
    }
    if (bidx >= c4 && bidx < c4 + 4) taken |= 1u << (bidx - c4);
    if (g == 0) out[OFF_TOPC_IDX + grow * 8 + rank] = (float)bidx;
    if (rank == 0) { tv0 = best; bidx0 = bidx; }
    if (rank == 1) { tv1 = best; bidx1 = bidx; }
  }

  if (g == 0) {
    out[OFF_TOPK_IDX + grow * 2 + 0] = (float)bidx0;
    out[OFF_TOPK_IDX + grow * 2 + 1] = (float)bidx1;
    const float e1  = expf(tv1 - tv0);
    const float den = 1.f + e1 + 1e-12f;
    out[OFF_TOPK_W + grow * 2 + 0] = 1.f / den;
    out[OFF_TOPK_W + grow * 2 + 1] = e1 / den;
  }
}

extern "C" void kernel_launch(void* const* d_in, const int* in_sizes, int n_in,
                              void* d_out, int out_size, void* d_ws, size_t ws_size,
                              hipStream_t stream) {
  const float* x = (const float*)d_in[0];
  const float* W = (const float*)d_in[1];
  float* out = (float*)d_out;

  unsigned short* w0 = (unsigned short*)d_ws;
  unsigned short* w1 = w0 + (size_t)Me * Dk;
  unsigned short* w2 = w1 + (size_t)Me * Dk;

  hipLaunchKernelGGL(wsplit_kernel, dim3((Me * Dk / 8) / 256), dim3(256), 0, stream, W, w0, w1, w2);
  hipLaunchKernelGGL(gating_mfma, dim3(Bq / ROWS), dim3(512), 0, stream, x, w0, w1, w2, out);
}